// Round 1
// baseline (1596.138 us; speedup 1.0000x reference)
//
#include <hip/hip_runtime.h>

#define N_NODES 50000
#define HIDDEN 128
#define NPB 16  // nodes per block in the linear kernel (50000 % 16 == 0 -> 3125 blocks)

// Transpose a 128x128 row-major W[out][in] -> Wt[in][out] so that lane-t reads
// Wt[k*128+t] are coalesced in the linear kernel.
__global__ void transpose_w(const float* __restrict__ W, float* __restrict__ Wt) {
    int tid = blockIdx.x * blockDim.x + threadIdx.x;  // 16384 threads
    int r = tid >> 7, c = tid & 127;
    Wt[c * HIDDEN + r] = W[r * HIDDEN + c];
}

__global__ void count_edges(const int* __restrict__ dst, int E, float* __restrict__ cnt) {
    int e = blockIdx.x * blockDim.x + threadIdx.x;
    if (e < E) atomicAdd(&cnt[dst[e]], 1.0f);
}

// One wave (64 lanes) per edge; lane l handles features [2l, 2l+1].
// Row load is one fully-coalesced 512B transaction per wave.
__global__ void scatter_feats(const float* __restrict__ feat,
                              const int* __restrict__ src,
                              const int* __restrict__ dst,
                              int E, float* __restrict__ agg) {
    int w = (int)((blockIdx.x * (size_t)blockDim.x + threadIdx.x) >> 6);
    int lane = threadIdx.x & 63;
    if (w >= E) return;
    int s = src[w];
    int d = dst[w];
    const float2 v = *reinterpret_cast<const float2*>(&feat[(size_t)s * HIDDEN + 2 * lane]);
    float* o = &agg[(size_t)d * HIDDEN + 2 * lane];
    atomicAdd(o, v.x);
    atomicAdd(o + 1, v.y);
}

// out[n][t] = relu?( sum_k agg_mean[n][k]*WlT[k][t] + xin[n][k]*WrT[k][t] + b[t] )
// 16 nodes per block; both row-vectors staged interleaved in LDS so the inner
// loop reads one broadcast ds_read_b64 per (r,k).
__global__ __launch_bounds__(128) void sage_linear(
    const float* __restrict__ agg, const float* __restrict__ cnt,
    const float* __restrict__ xin, const float* __restrict__ WlT,
    const float* __restrict__ WrT, const float* __restrict__ bias,
    float* __restrict__ out, int relu) {
    __shared__ float sh[NPB][HIDDEN][2];  // [r][k][{agg_mean, x}] -> 16 KiB
    const int t = threadIdx.x;
    const int n0 = blockIdx.x * NPB;

    for (int r = 0; r < NPB; ++r) {
        const int node = n0 + r;
        const float inv = 1.0f / fmaxf(cnt[node], 1.0f);
        sh[r][t][0] = agg[(size_t)node * HIDDEN + t] * inv;
        sh[r][t][1] = xin[(size_t)node * HIDDEN + t];
    }
    __syncthreads();

    const float b = bias[t];
    float acc[NPB];
#pragma unroll
    for (int r = 0; r < NPB; ++r) acc[r] = b;

#pragma unroll 4
    for (int k = 0; k < HIDDEN; ++k) {
        const float wl = WlT[k * HIDDEN + t];
        const float wr = WrT[k * HIDDEN + t];
#pragma unroll
        for (int r = 0; r < NPB; ++r) {
            acc[r] += sh[r][k][0] * wl + sh[r][k][1] * wr;
        }
    }

    for (int r = 0; r < NPB; ++r) {
        float v = acc[r];
        if (relu) v = fmaxf(v, 0.0f);
        out[(size_t)(n0 + r) * HIDDEN + t] = v;
    }
}

extern "C" void kernel_launch(void* const* d_in, const int* in_sizes, int n_in,
                              void* d_out, int out_size, void* d_ws, size_t ws_size,
                              hipStream_t stream) {
    const float* x   = (const float*)d_in[0];
    const int*   ei  = (const int*)d_in[1];
    const float* W1l = (const float*)d_in[2];
    const float* b1  = (const float*)d_in[3];
    const float* W1r = (const float*)d_in[4];
    const float* W2l = (const float*)d_in[5];
    const float* b2  = (const float*)d_in[6];
    const float* W2r = (const float*)d_in[7];

    const int E = in_sizes[1] / 2;
    const int* src = ei;
    const int* dst = ei + E;

    float* ws   = (float*)d_ws;
    float* cnt  = ws;                                   // 50000
    float* agg  = ws + N_NODES;                         // 6.4M
    float* W1lT = agg + (size_t)N_NODES * HIDDEN;       // 16384 each
    float* W1rT = W1lT + HIDDEN * HIDDEN;
    float* W2lT = W1rT + HIDDEN * HIDDEN;
    float* W2rT = W2lT + HIDDEN * HIDDEN;
    float* h    = (float*)d_out;  // layer-1 activations live in d_out; final linear
                                  // reads its own row into LDS before overwriting.

    // zero cnt + agg (contiguous)
    hipMemsetAsync(ws, 0, (size_t)(N_NODES + (size_t)N_NODES * HIDDEN) * sizeof(float), stream);

    transpose_w<<<64, 256, 0, stream>>>(W1l, W1lT);
    transpose_w<<<64, 256, 0, stream>>>(W1r, W1rT);
    transpose_w<<<64, 256, 0, stream>>>(W2l, W2lT);
    transpose_w<<<64, 256, 0, stream>>>(W2r, W2rT);

    count_edges<<<(E + 255) / 256, 256, 0, stream>>>(dst, E, cnt);

    // ---- layer 1 ----
    scatter_feats<<<(E + 3) / 4, 256, 0, stream>>>(x, src, dst, E, agg);
    sage_linear<<<N_NODES / NPB, 128, 0, stream>>>(agg, cnt, x, W1lT, W1rT, b1, h, 1);

    // ---- layer 2 ----
    hipMemsetAsync(agg, 0, (size_t)N_NODES * HIDDEN * sizeof(float), stream);
    scatter_feats<<<(E + 3) / 4, 256, 0, stream>>>(h, src, dst, E, agg);
    sage_linear<<<N_NODES / NPB, 128, 0, stream>>>(agg, cnt, h, W2lT, W2rT, b2, (float*)d_out, 0);
}

// Round 2
// 478.182 us; speedup vs baseline: 3.3379x; 3.3379x over previous
//
#include <hip/hip_runtime.h>

#define N_NODES 50000
#define HIDDEN 128
#define NPB 16  // nodes per block in the linear kernel

// Transpose a 128x128 row-major W[out][in] -> Wt[in][out] so lane-t reads
// Wt[k*128+t] are coalesced in the linear kernel.
__global__ void transpose_w(const float* __restrict__ W, float* __restrict__ Wt) {
    int tid = blockIdx.x * blockDim.x + threadIdx.x;  // 16384 threads
    int r = tid >> 7, c = tid & 127;
    Wt[c * HIDDEN + r] = W[r * HIDDEN + c];
}

__global__ void hist_deg(const int* __restrict__ dst, int E, int* __restrict__ deg) {
    int e = blockIdx.x * blockDim.x + threadIdx.x;
    if (e < E) atomicAdd(&deg[dst[e]], 1);
}

// Single-block exclusive scan of deg[0..n) -> row_start[0..n]; shfl-based,
// 4 syncthreads per 1024-chunk (49 chunks).
__global__ __launch_bounds__(1024) void scan_deg(const int* __restrict__ deg, int n,
                                                 int* __restrict__ row_start) {
    __shared__ int wsum[16];
    __shared__ int s_carry;
    const int tid = threadIdx.x;
    const int lane = tid & 63, wid = tid >> 6;
    if (tid == 0) s_carry = 0;
    __syncthreads();
    for (int base = 0; base < n; base += 1024) {
        const int i = base + tid;
        const int v = (i < n) ? deg[i] : 0;
        int incl = v;
        for (int off = 1; off < 64; off <<= 1) {
            int t = __shfl_up(incl, off);
            if (lane >= off) incl += t;
        }
        if (lane == 63) wsum[wid] = incl;
        __syncthreads();
        if (wid == 0) {
            int wv = (lane < 16) ? wsum[lane] : 0;
            int wincl = wv;
            for (int off = 1; off < 16; off <<= 1) {
                int t = __shfl_up(wincl, off);
                if (lane >= off) wincl += t;
            }
            if (lane < 16) wsum[lane] = wincl - wv;  // exclusive wave offsets
        }
        __syncthreads();
        const int excl = s_carry + wsum[wid] + incl - v;
        if (i < n) row_start[i] = excl;
        __syncthreads();
        if (tid == 1023) s_carry = excl + v;
        __syncthreads();
    }
    if (tid == 0) row_start[n] = s_carry;
}

__global__ void bucket_edges(const int* __restrict__ src, const int* __restrict__ dst,
                             int E, const int* __restrict__ row_start,
                             int* __restrict__ cursor, int* __restrict__ sorted_src) {
    int e = blockIdx.x * blockDim.x + threadIdx.x;
    if (e < E) {
        int d = dst[e];
        int p = atomicAdd(&cursor[d], 1);
        sorted_src[row_start[d] + p] = src[e];
    }
}

// One wave per dst node; lane l owns features [2l,2l+1]. Gather in-neighbor
// rows (coalesced 512B per edge), accumulate, divide by degree, single write.
__global__ __launch_bounds__(256) void aggregate_mean(
    const float* __restrict__ feat, const int* __restrict__ row_start,
    const int* __restrict__ sorted_src, float* __restrict__ agg) {
    const int node = blockIdx.x * 4 + (threadIdx.x >> 6);
    const int lane = threadIdx.x & 63;
    if (node >= N_NODES) return;
    const int beg = row_start[node], end = row_start[node + 1];
    float2 acc0 = {0.f, 0.f}, acc1 = {0.f, 0.f};
    int j = beg;
    for (; j + 1 < end; j += 2) {  // 2 independent gathers in flight
        int s0 = sorted_src[j], s1 = sorted_src[j + 1];
        float2 v0 = *reinterpret_cast<const float2*>(&feat[(size_t)s0 * HIDDEN + 2 * lane]);
        float2 v1 = *reinterpret_cast<const float2*>(&feat[(size_t)s1 * HIDDEN + 2 * lane]);
        acc0.x += v0.x; acc0.y += v0.y;
        acc1.x += v1.x; acc1.y += v1.y;
    }
    if (j < end) {
        int s0 = sorted_src[j];
        float2 v0 = *reinterpret_cast<const float2*>(&feat[(size_t)s0 * HIDDEN + 2 * lane]);
        acc0.x += v0.x; acc0.y += v0.y;
    }
    const int d = end - beg;
    const float inv = d ? 1.0f / (float)d : 0.0f;
    float2 o = {(acc0.x + acc1.x) * inv, (acc0.y + acc1.y) * inv};
    *reinterpret_cast<float2*>(&agg[(size_t)node * HIDDEN + 2 * lane]) = o;
}

// out[n][t] = relu?( sum_k agg[n][k]*WlT[k][t] + xin[n][k]*WrT[k][t] + b[t] )
__global__ __launch_bounds__(128) void sage_linear(
    const float* __restrict__ agg, const float* __restrict__ xin,
    const float* __restrict__ WlT, const float* __restrict__ WrT,
    const float* __restrict__ bias, float* __restrict__ out, int relu) {
    __shared__ float sh[NPB][HIDDEN][2];  // [r][k][{agg, x}] -> 16 KiB
    const int t = threadIdx.x;
    const int n0 = blockIdx.x * NPB;

    for (int r = 0; r < NPB; ++r) {
        const int node = n0 + r;
        sh[r][t][0] = agg[(size_t)node * HIDDEN + t];
        sh[r][t][1] = xin[(size_t)node * HIDDEN + t];
    }
    __syncthreads();

    const float b = bias[t];
    float acc[NPB];
#pragma unroll
    for (int r = 0; r < NPB; ++r) acc[r] = b;

#pragma unroll 4
    for (int k = 0; k < HIDDEN; ++k) {
        const float wl = WlT[k * HIDDEN + t];
        const float wr = WrT[k * HIDDEN + t];
#pragma unroll
        for (int r = 0; r < NPB; ++r) {
            acc[r] += sh[r][k][0] * wl + sh[r][k][1] * wr;
        }
    }

    for (int r = 0; r < NPB; ++r) {
        float v = acc[r];
        if (relu) v = fmaxf(v, 0.0f);
        out[(size_t)(n0 + r) * HIDDEN + t] = v;
    }
}

extern "C" void kernel_launch(void* const* d_in, const int* in_sizes, int n_in,
                              void* d_out, int out_size, void* d_ws, size_t ws_size,
                              hipStream_t stream) {
    const float* x   = (const float*)d_in[0];
    const int*   ei  = (const int*)d_in[1];
    const float* W1l = (const float*)d_in[2];
    const float* b1  = (const float*)d_in[3];
    const float* W1r = (const float*)d_in[4];
    const float* W2l = (const float*)d_in[5];
    const float* b2  = (const float*)d_in[6];
    const float* W2r = (const float*)d_in[7];

    const int E = in_sizes[1] / 2;
    const int* src = ei;
    const int* dst = ei + E;

    // ---- workspace layout ----
    int* iws        = (int*)d_ws;
    int* deg        = iws;                    // 50000
    int* cursor     = deg + N_NODES;          // 50000  (contiguous with deg for one memset)
    int* row_start  = cursor + N_NODES;       // 50001
    int* sorted_src = row_start + N_NODES + 1;                  // E
    float* agg  = (float*)(sorted_src + E);                     // 50000*128
    float* W1lT = agg + (size_t)N_NODES * HIDDEN;
    float* W1rT = W1lT + HIDDEN * HIDDEN;
    float* W2lT = W1rT + HIDDEN * HIDDEN;
    float* W2rT = W2lT + HIDDEN * HIDDEN;
    float* h    = (float*)d_out;  // layer-1 activations live in d_out

    hipMemsetAsync(iws, 0, (size_t)(2 * N_NODES) * sizeof(int), stream);  // deg+cursor

    transpose_w<<<64, 256, 0, stream>>>(W1l, W1lT);
    transpose_w<<<64, 256, 0, stream>>>(W1r, W1rT);
    transpose_w<<<64, 256, 0, stream>>>(W2l, W2lT);
    transpose_w<<<64, 256, 0, stream>>>(W2r, W2rT);

    // ---- CSR build (shared by both layers) ----
    hist_deg<<<(E + 255) / 256, 256, 0, stream>>>(dst, E, deg);
    scan_deg<<<1, 1024, 0, stream>>>(deg, N_NODES, row_start);
    bucket_edges<<<(E + 255) / 256, 256, 0, stream>>>(src, dst, E, row_start, cursor, sorted_src);

    // ---- layer 1 ----
    aggregate_mean<<<(N_NODES + 3) / 4, 256, 0, stream>>>(x, row_start, sorted_src, agg);
    sage_linear<<<N_NODES / NPB, 128, 0, stream>>>(agg, x, W1lT, W1rT, b1, h, 1);

    // ---- layer 2 ----
    aggregate_mean<<<(N_NODES + 3) / 4, 256, 0, stream>>>(h, row_start, sorted_src, agg);
    sage_linear<<<N_NODES / NPB, 128, 0, stream>>>(agg, h, W2lT, W2rT, b2, (float*)d_out, 0);
}

// Round 3
// 284.765 us; speedup vs baseline: 5.6051x; 1.6792x over previous
//
#include <hip/hip_runtime.h>

#define N_NODES 50000
#define HIDDEN 128

typedef __attribute__((ext_vector_type(8))) short short8;
typedef __attribute__((ext_vector_type(4))) float f32x4;

__device__ __forceinline__ unsigned short f2bf(float f) {
    union { float f; unsigned int u; } a; a.f = f;
    unsigned int u = a.u;
    u += 0x7FFFu + ((u >> 16) & 1u);  // RNE
    return (unsigned short)(u >> 16);
}
__device__ __forceinline__ float bf2f(unsigned int bits16) {
    union { unsigned int u; float f; } a; a.u = bits16 << 16;
    return a.f;
}

// Pack Wcat[256][128] (rows 0..127 = Wl^T, 128..255 = Wr^T) into MFMA-B
// fragment order: Wp[((ks*8+nf)*64+lane)*8+j] = Wcat[ks*32+(lane>>4)*8+j][nf*16+(lane&15)]
__global__ void pack_w(const float* __restrict__ Wl, const float* __restrict__ Wr,
                       unsigned short* __restrict__ Wp) {
    int tid = blockIdx.x * blockDim.x + threadIdx.x;  // 32768
    int j = tid & 7, lane = (tid >> 3) & 63, nf = (tid >> 9) & 7, ks = tid >> 12;
    int k = ks * 32 + ((lane >> 4) * 8) + j;
    int t = nf * 16 + (lane & 15);
    float v = (k < 128) ? Wl[t * 128 + k] : Wr[t * 128 + (k - 128)];
    Wp[tid] = f2bf(v);
}

__global__ void cast_bf16(const float* __restrict__ x, unsigned short* __restrict__ xb, int n4) {
    int i = blockIdx.x * blockDim.x + threadIdx.x;
    if (i >= n4) return;
    float4 v = reinterpret_cast<const float4*>(x)[i];
    ushort4 o = make_ushort4(f2bf(v.x), f2bf(v.y), f2bf(v.z), f2bf(v.w));
    reinterpret_cast<ushort4*>(xb)[i] = o;
}

__global__ void hist_deg(const int* __restrict__ dst, int E, int* __restrict__ deg) {
    int e = blockIdx.x * blockDim.x + threadIdx.x;
    if (e < E) atomicAdd(&deg[dst[e]], 1);
}

// Single-block exclusive scan of deg[0..n) -> row_start[0..n].
__global__ __launch_bounds__(1024) void scan_deg(const int* __restrict__ deg, int n,
                                                 int* __restrict__ row_start) {
    __shared__ int wsum[16];
    __shared__ int s_carry;
    const int tid = threadIdx.x;
    const int lane = tid & 63, wid = tid >> 6;
    if (tid == 0) s_carry = 0;
    __syncthreads();
    for (int base = 0; base < n; base += 1024) {
        const int i = base + tid;
        const int v = (i < n) ? deg[i] : 0;
        int incl = v;
        for (int off = 1; off < 64; off <<= 1) {
            int t = __shfl_up(incl, off);
            if (lane >= off) incl += t;
        }
        if (lane == 63) wsum[wid] = incl;
        __syncthreads();
        if (wid == 0) {
            int wv = (lane < 16) ? wsum[lane] : 0;
            int wincl = wv;
            for (int off = 1; off < 16; off <<= 1) {
                int t = __shfl_up(wincl, off);
                if (lane >= off) wincl += t;
            }
            if (lane < 16) wsum[lane] = wincl - wv;
        }
        __syncthreads();
        const int excl = s_carry + wsum[wid] + incl - v;
        if (i < n) row_start[i] = excl;
        __syncthreads();
        if (tid == 1023) s_carry = excl + v;
        __syncthreads();
    }
    if (tid == 0) row_start[n] = s_carry;
}

__global__ void bucket_edges(const int* __restrict__ src, const int* __restrict__ dst,
                             int E, const int* __restrict__ row_start,
                             int* __restrict__ cursor, int* __restrict__ sorted_src) {
    int e = blockIdx.x * blockDim.x + threadIdx.x;
    if (e < E) {
        int d = dst[e];
        int p = atomicAdd(&cursor[d], 1);
        sorted_src[row_start[d] + p] = src[e];
    }
}

// One wave per dst node; lane l owns features [2l,2l+1] (one 4B load per edge).
__global__ __launch_bounds__(256) void aggregate_mean_bf16(
    const unsigned short* __restrict__ featb, const int* __restrict__ row_start,
    const int* __restrict__ sorted_src, unsigned short* __restrict__ aggb) {
    const int node = blockIdx.x * 4 + (threadIdx.x >> 6);
    const int lane = threadIdx.x & 63;
    if (node >= N_NODES) return;
    const int beg = row_start[node], end = row_start[node + 1];
    float a0 = 0.f, a1 = 0.f, b0 = 0.f, b1 = 0.f;
    int j = beg;
    for (; j + 1 < end; j += 2) {
        int s0 = sorted_src[j], s1 = sorted_src[j + 1];
        unsigned int u0 = *reinterpret_cast<const unsigned int*>(&featb[(size_t)s0 * HIDDEN + 2 * lane]);
        unsigned int u1 = *reinterpret_cast<const unsigned int*>(&featb[(size_t)s1 * HIDDEN + 2 * lane]);
        a0 += bf2f(u0 & 0xffffu); a1 += bf2f(u0 >> 16);
        b0 += bf2f(u1 & 0xffffu); b1 += bf2f(u1 >> 16);
    }
    if (j < end) {
        unsigned int u0 = *reinterpret_cast<const unsigned int*>(&featb[(size_t)sorted_src[j] * HIDDEN + 2 * lane]);
        a0 += bf2f(u0 & 0xffffu); a1 += bf2f(u0 >> 16);
    }
    const int d = end - beg;
    const float inv = d ? 1.0f / (float)d : 0.0f;
    unsigned int o = (unsigned int)f2bf((a0 + b0) * inv) | ((unsigned int)f2bf((a1 + b1) * inv) << 16);
    *reinterpret_cast<unsigned int*>(&aggb[(size_t)node * HIDDEN + 2 * lane]) = o;
}

// out[n][t] = relu?( sum_k aggb[n][k]*Wl[t][k] + xb[n][k]*Wr[t][k] + b[t] )
// 4 waves/block (2M x 2N), 64-row x 128-col tile, K=256 in 8 steps of 32.
// Layer 1 (WRITE_BF16_RELU=1) writes bf16 IN-PLACE over xb: each block reads
// only its own 64 rows (k-loop) before its epilogue stores -> no hazard.
template <int WRITE_BF16_RELU>
__global__ __launch_bounds__(256) void mfma_linear(
    const unsigned short* aggb, const unsigned short* xb,
    const unsigned short* __restrict__ Wp, const float* __restrict__ bias,
    unsigned short* out_b, float* out_f) {
    const int lane = threadIdx.x & 63;
    const int wave = threadIdx.x >> 6;
    const int wm = wave >> 1, wn = wave & 1;
    const int rowbase = blockIdx.x * 64 + wm * 32;
    const int colbase = wn * 64;
    const int l15 = lane & 15, l4 = lane >> 4;

    f32x4 acc[2][4];
#pragma unroll
    for (int m = 0; m < 2; ++m)
#pragma unroll
        for (int nf = 0; nf < 4; ++nf) acc[m][nf] = (f32x4){0.f, 0.f, 0.f, 0.f};

#pragma unroll
    for (int ks = 0; ks < 8; ++ks) {
        const unsigned short* Asrc = (ks < 4) ? aggb : xb;
        const int koff = (ks & 3) * 32 + l4 * 8;
        short8 a[2];
#pragma unroll
        for (int m = 0; m < 2; ++m) {
            int row = rowbase + m * 16 + l15;
            if (row >= N_NODES) row = N_NODES - 1;
            a[m] = *reinterpret_cast<const short8*>(&Asrc[(size_t)row * HIDDEN + koff]);
        }
#pragma unroll
        for (int nf = 0; nf < 4; ++nf) {
            const int nfg = (colbase >> 4) + nf;
            short8 b = *reinterpret_cast<const short8*>(&Wp[(((size_t)ks * 8 + nfg) * 64 + lane) * 8]);
            acc[0][nf] = __builtin_amdgcn_mfma_f32_16x16x32_bf16(a[0], b, acc[0][nf], 0, 0, 0);
            acc[1][nf] = __builtin_amdgcn_mfma_f32_16x16x32_bf16(a[1], b, acc[1][nf], 0, 0, 0);
        }
    }

#pragma unroll
    for (int nf = 0; nf < 4; ++nf) {
        const int col = colbase + nf * 16 + l15;
        const float bv = bias[col];
#pragma unroll
        for (int m = 0; m < 2; ++m) {
#pragma unroll
            for (int r = 0; r < 4; ++r) {
                const int row = rowbase + m * 16 + l4 * 4 + r;
                if (row < N_NODES) {
                    float v = acc[m][nf][r] + bv;
                    if (WRITE_BF16_RELU) {
                        v = fmaxf(v, 0.0f);
                        out_b[(size_t)row * HIDDEN + col] = f2bf(v);
                    } else {
                        out_f[(size_t)row * HIDDEN + col] = v;
                    }
                }
            }
        }
    }
}

extern "C" void kernel_launch(void* const* d_in, const int* in_sizes, int n_in,
                              void* d_out, int out_size, void* d_ws, size_t ws_size,
                              hipStream_t stream) {
    const float* x   = (const float*)d_in[0];
    const int*   ei  = (const int*)d_in[1];
    const float* W1l = (const float*)d_in[2];
    const float* b1  = (const float*)d_in[3];
    const float* W1r = (const float*)d_in[4];
    const float* W2l = (const float*)d_in[5];
    const float* b2  = (const float*)d_in[6];
    const float* W2r = (const float*)d_in[7];

    const int E = in_sizes[1] / 2;
    const int* src = ei;
    const int* dst = ei + E;

    // ---- workspace layout (16B-aligned sections) ----
    int* iws        = (int*)d_ws;
    int* deg        = iws;                      // 50000
    int* cursor     = deg + N_NODES;            // 50000
    int* row_start  = cursor + N_NODES;         // 50001 (+pad to 150016)
    int* sorted_src = iws + 150016;             // 800000 -> ends at 950016 ints (16B aligned)
    unsigned short* xb   = (unsigned short*)(iws + 950016);     // 6.4M bf16 (h overwrites in-place)
    unsigned short* aggb = xb + (size_t)N_NODES * HIDDEN;       // 6.4M bf16
    unsigned short* Wp1  = aggb + (size_t)N_NODES * HIDDEN;     // 32768 bf16
    unsigned short* Wp2  = Wp1 + 256 * HIDDEN;                  // 32768 bf16

    hipMemsetAsync(iws, 0, (size_t)(2 * N_NODES) * sizeof(int), stream);  // deg+cursor

    pack_w<<<128, 256, 0, stream>>>(W1l, W1r, Wp1);
    pack_w<<<128, 256, 0, stream>>>(W2l, W2r, Wp2);
    cast_bf16<<<(N_NODES * HIDDEN / 4 + 255) / 256, 256, 0, stream>>>(x, xb, N_NODES * HIDDEN / 4);

    // ---- CSR build (shared by both layers) ----
    hist_deg<<<(E + 255) / 256, 256, 0, stream>>>(dst, E, deg);
    scan_deg<<<1, 1024, 0, stream>>>(deg, N_NODES, row_start);
    bucket_edges<<<(E + 255) / 256, 256, 0, stream>>>(src, dst, E, row_start, cursor, sorted_src);

    const int aggGrid = (N_NODES + 3) / 4;
    const int linGrid = (N_NODES + 63) / 64;

    // ---- layer 1 ----
    aggregate_mean_bf16<<<aggGrid, 256, 0, stream>>>(xb, row_start, sorted_src, aggb);
    mfma_linear<1><<<linGrid, 256, 0, stream>>>(aggb, xb, Wp1, b1, xb, nullptr);

    // ---- layer 2 ----
    aggregate_mean_bf16<<<aggGrid, 256, 0, stream>>>(xb, row_start, sorted_src, aggb);
    mfma_linear<0><<<linGrid, 256, 0, stream>>>(aggb, xb, Wp2, b2, nullptr, (float*)d_out);
}

// Round 4
// 204.977 us; speedup vs baseline: 7.7869x; 1.3893x over previous
//
#include <hip/hip_runtime.h>

#define N_NODES 50000
#define HIDDEN 128

typedef __attribute__((ext_vector_type(8))) short short8;
typedef __attribute__((ext_vector_type(4))) float f32x4;

__device__ __forceinline__ unsigned short f2bf(float f) {
    union { float f; unsigned int u; } a; a.f = f;
    unsigned int u = a.u;
    u += 0x7FFFu + ((u >> 16) & 1u);  // RNE
    return (unsigned short)(u >> 16);
}
__device__ __forceinline__ float bf2f(unsigned int bits16) {
    union { unsigned int u; float f; } a; a.u = bits16 << 16;
    return a.f;
}

// Pack Wcat[256][128] (rows 0..127 = Wl^T, 128..255 = Wr^T) into MFMA-B
// fragment order: Wp[((ks*8+nf)*64+lane)*8+j] = Wcat[ks*32+(lane>>4)*8+j][nf*16+(lane&15)]
__global__ void pack_w(const float* __restrict__ Wl, const float* __restrict__ Wr,
                       unsigned short* __restrict__ Wp) {
    int tid = blockIdx.x * blockDim.x + threadIdx.x;  // 32768
    int j = tid & 7, lane = (tid >> 3) & 63, nf = (tid >> 9) & 7, ks = tid >> 12;
    int k = ks * 32 + ((lane >> 4) * 8) + j;
    int t = nf * 16 + (lane & 15);
    float v = (k < 128) ? Wl[t * 128 + k] : Wr[t * 128 + (k - 128)];
    Wp[tid] = f2bf(v);
}

__global__ void cast_bf16(const float* __restrict__ x, unsigned short* __restrict__ xb, int n4) {
    int i = blockIdx.x * blockDim.x + threadIdx.x;
    if (i >= n4) return;
    float4 v = reinterpret_cast<const float4*>(x)[i];
    ushort4 o = make_ushort4(f2bf(v.x), f2bf(v.y), f2bf(v.z), f2bf(v.w));
    reinterpret_cast<ushort4*>(xb)[i] = o;
}

__global__ void hist_deg(const int* __restrict__ dst, int E, int* __restrict__ deg) {
    int e = blockIdx.x * blockDim.x + threadIdx.x;
    if (e < E) atomicAdd(&deg[dst[e]], 1);
}

// ---- 3-phase parallel exclusive scan of deg[0..n) -> row_start[0..n] ----
__global__ __launch_bounds__(1024) void scan_p1(const int* __restrict__ deg, int n,
                                                int* __restrict__ bsum) {
    __shared__ int ws[16];
    const int i = blockIdx.x * 1024 + threadIdx.x;
    const int lane = threadIdx.x & 63, wid = threadIdx.x >> 6;
    int v = (i < n) ? deg[i] : 0;
#pragma unroll
    for (int off = 32; off; off >>= 1) v += __shfl_down(v, off);
    if (lane == 0) ws[wid] = v;
    __syncthreads();
    if (wid == 0) {
        int s = (lane < 16) ? ws[lane] : 0;
#pragma unroll
        for (int off = 8; off; off >>= 1) s += __shfl_down(s, off);
        if (lane == 0) bsum[blockIdx.x] = s;
    }
}

// one wave; nb <= 64. Exclusive-scans bsum in place, writes total to row_start[n].
__global__ void scan_p2(int* __restrict__ bsum, int nb, int n, int* __restrict__ row_start) {
    const int lane = threadIdx.x;
    int v = (lane < nb) ? bsum[lane] : 0;
    int incl = v;
#pragma unroll
    for (int off = 1; off < 64; off <<= 1) {
        int t = __shfl_up(incl, off);
        if (lane >= off) incl += t;
    }
    if (lane < nb) bsum[lane] = incl - v;
    if (lane == 63) row_start[n] = incl;
}

__global__ __launch_bounds__(1024) void scan_p3(const int* __restrict__ deg, int n,
                                                const int* __restrict__ bsum,
                                                int* __restrict__ row_start) {
    __shared__ int ws[16];
    const int i = blockIdx.x * 1024 + threadIdx.x;
    const int lane = threadIdx.x & 63, wid = threadIdx.x >> 6;
    const int v = (i < n) ? deg[i] : 0;
    int incl = v;
#pragma unroll
    for (int off = 1; off < 64; off <<= 1) {
        int t = __shfl_up(incl, off);
        if (lane >= off) incl += t;
    }
    if (lane == 63) ws[wid] = incl;
    __syncthreads();
    if (wid == 0) {
        int wv = (lane < 16) ? ws[lane] : 0;
        int wincl = wv;
#pragma unroll
        for (int off = 1; off < 16; off <<= 1) {
            int t = __shfl_up(wincl, off);
            if (lane >= off) wincl += t;
        }
        if (lane < 16) ws[lane] = wincl - wv;
    }
    __syncthreads();
    if (i < n) row_start[i] = bsum[blockIdx.x] + ws[wid] + incl - v;
}

__global__ void bucket_edges(const int* __restrict__ src, const int* __restrict__ dst,
                             int E, const int* __restrict__ row_start,
                             int* __restrict__ cursor, int* __restrict__ sorted_src) {
    int e = blockIdx.x * blockDim.x + threadIdx.x;
    if (e < E) {
        int d = dst[e];
        int p = atomicAdd(&cursor[d], 1);
        sorted_src[row_start[d] + p] = src[e];
    }
}

// 32 lanes per node (lane owns 4 features via ushort4), 2 nodes per wave,
// unroll 4 -> 8 row-gathers in flight per wave.
__global__ __launch_bounds__(256) void aggregate_mean_bf16(
    const unsigned short* __restrict__ featb, const int* __restrict__ row_start,
    const int* __restrict__ sorted_src, unsigned short* __restrict__ aggb) {
    const int node = blockIdx.x * 8 + (threadIdx.x >> 5);
    const int l = threadIdx.x & 31;
    if (node >= N_NODES) return;
    const int beg = row_start[node], end = row_start[node + 1];
    float acc[4][4];
#pragma unroll
    for (int u = 0; u < 4; ++u)
#pragma unroll
        for (int f = 0; f < 4; ++f) acc[u][f] = 0.f;

    int j = beg;
    for (; j + 3 < end; j += 4) {
#pragma unroll
        for (int u = 0; u < 4; ++u) {
            const int s = sorted_src[j + u];
            const ushort4 v = *reinterpret_cast<const ushort4*>(&featb[(size_t)s * HIDDEN + 4 * l]);
            acc[u][0] += bf2f(v.x); acc[u][1] += bf2f(v.y);
            acc[u][2] += bf2f(v.z); acc[u][3] += bf2f(v.w);
        }
    }
    for (; j < end; ++j) {
        const int s = sorted_src[j];
        const ushort4 v = *reinterpret_cast<const ushort4*>(&featb[(size_t)s * HIDDEN + 4 * l]);
        acc[0][0] += bf2f(v.x); acc[0][1] += bf2f(v.y);
        acc[0][2] += bf2f(v.z); acc[0][3] += bf2f(v.w);
    }
    const int d = end - beg;
    const float inv = d ? 1.0f / (float)d : 0.0f;
    ushort4 o;
    o.x = f2bf((acc[0][0] + acc[1][0] + acc[2][0] + acc[3][0]) * inv);
    o.y = f2bf((acc[0][1] + acc[1][1] + acc[2][1] + acc[3][1]) * inv);
    o.z = f2bf((acc[0][2] + acc[1][2] + acc[2][2] + acc[3][2]) * inv);
    o.w = f2bf((acc[0][3] + acc[1][3] + acc[2][3] + acc[3][3]) * inv);
    *reinterpret_cast<ushort4*>(&aggb[(size_t)node * HIDDEN + 4 * l]) = o;
}

// out[n][t] = relu?( sum_k aggb[n][k]*Wl[t][k] + xb[n][k]*Wr[t][k] + b[t] )
// 4 waves/block (2M x 2N), 64-row x 128-col tile, K=256 in 8 steps of 32.
// Layer 1 (WRITE_BF16_RELU=1) writes bf16 IN-PLACE over xb: each block reads
// only its own 64 rows (k-loop) before its epilogue stores -> no hazard.
template <int WRITE_BF16_RELU>
__global__ __launch_bounds__(256) void mfma_linear(
    const unsigned short* aggb, const unsigned short* xb,
    const unsigned short* __restrict__ Wp, const float* __restrict__ bias,
    unsigned short* out_b, float* out_f) {
    const int lane = threadIdx.x & 63;
    const int wave = threadIdx.x >> 6;
    const int wm = wave >> 1, wn = wave & 1;
    const int rowbase = blockIdx.x * 64 + wm * 32;
    const int colbase = wn * 64;
    const int l15 = lane & 15, l4 = lane >> 4;

    f32x4 acc[2][4];
#pragma unroll
    for (int m = 0; m < 2; ++m)
#pragma unroll
        for (int nf = 0; nf < 4; ++nf) acc[m][nf] = (f32x4){0.f, 0.f, 0.f, 0.f};

#pragma unroll
    for (int ks = 0; ks < 8; ++ks) {
        const unsigned short* Asrc = (ks < 4) ? aggb : xb;
        const int koff = (ks & 3) * 32 + l4 * 8;
        short8 a[2];
#pragma unroll
        for (int m = 0; m < 2; ++m) {
            int row = rowbase + m * 16 + l15;
            if (row >= N_NODES) row = N_NODES - 1;
            a[m] = *reinterpret_cast<const short8*>(&Asrc[(size_t)row * HIDDEN + koff]);
        }
#pragma unroll
        for (int nf = 0; nf < 4; ++nf) {
            const int nfg = (colbase >> 4) + nf;
            short8 b = *reinterpret_cast<const short8*>(&Wp[(((size_t)ks * 8 + nfg) * 64 + lane) * 8]);
            acc[0][nf] = __builtin_amdgcn_mfma_f32_16x16x32_bf16(a[0], b, acc[0][nf], 0, 0, 0);
            acc[1][nf] = __builtin_amdgcn_mfma_f32_16x16x32_bf16(a[1], b, acc[1][nf], 0, 0, 0);
        }
    }

#pragma unroll
    for (int nf = 0; nf < 4; ++nf) {
        const int col = colbase + nf * 16 + l15;
        const float bv = bias[col];
#pragma unroll
        for (int m = 0; m < 2; ++m) {
#pragma unroll
            for (int r = 0; r < 4; ++r) {
                const int row = rowbase + m * 16 + l4 * 4 + r;
                if (row < N_NODES) {
                    float v = acc[m][nf][r] + bv;
                    if (WRITE_BF16_RELU) {
                        v = fmaxf(v, 0.0f);
                        out_b[(size_t)row * HIDDEN + col] = f2bf(v);
                    } else {
                        out_f[(size_t)row * HIDDEN + col] = v;
                    }
                }
            }
        }
    }
}

extern "C" void kernel_launch(void* const* d_in, const int* in_sizes, int n_in,
                              void* d_out, int out_size, void* d_ws, size_t ws_size,
                              hipStream_t stream) {
    const float* x   = (const float*)d_in[0];
    const int*   ei  = (const int*)d_in[1];
    const float* W1l = (const float*)d_in[2];
    const float* b1  = (const float*)d_in[3];
    const float* W1r = (const float*)d_in[4];
    const float* W2l = (const float*)d_in[5];
    const float* b2  = (const float*)d_in[6];
    const float* W2r = (const float*)d_in[7];

    const int E = in_sizes[1] / 2;
    const int* src = ei;
    const int* dst = ei + E;

    // ---- workspace layout ----
    int* iws        = (int*)d_ws;
    int* deg        = iws;                      // @0      50000
    int* cursor     = iws + 50000;              // @50000  50000
    int* row_start  = iws + 100000;             // @100000 50001
    int* bsum       = iws + 150016;             // @150016 64
    int* sorted_src = iws + 150080;             // @150080 800000 -> ends 950080 (16B aligned)
    unsigned short* xb   = (unsigned short*)(iws + 950080);   // 6.4M bf16 (h overwrites in-place)
    unsigned short* aggb = xb + (size_t)N_NODES * HIDDEN;     // 6.4M bf16
    unsigned short* Wp1  = aggb + (size_t)N_NODES * HIDDEN;   // 32768 bf16
    unsigned short* Wp2  = Wp1 + 256 * HIDDEN;                // 32768 bf16

    hipMemsetAsync(iws, 0, (size_t)(2 * N_NODES) * sizeof(int), stream);  // deg+cursor

    pack_w<<<128, 256, 0, stream>>>(W1l, W1r, Wp1);
    pack_w<<<128, 256, 0, stream>>>(W2l, W2r, Wp2);
    cast_bf16<<<(N_NODES * HIDDEN / 4 + 255) / 256, 256, 0, stream>>>(x, xb, N_NODES * HIDDEN / 4);

    // ---- CSR build (shared by both layers) ----
    const int nScan = (N_NODES + 1023) / 1024;  // 49
    hist_deg<<<(E + 255) / 256, 256, 0, stream>>>(dst, E, deg);
    scan_p1<<<nScan, 1024, 0, stream>>>(deg, N_NODES, bsum);
    scan_p2<<<1, 64, 0, stream>>>(bsum, nScan, N_NODES, row_start);
    scan_p3<<<nScan, 1024, 0, stream>>>(deg, N_NODES, bsum, row_start);
    bucket_edges<<<(E + 255) / 256, 256, 0, stream>>>(src, dst, E, row_start, cursor, sorted_src);

    const int aggGrid = (N_NODES + 7) / 8;
    const int linGrid = (N_NODES + 63) / 64;

    // ---- layer 1 ----
    aggregate_mean_bf16<<<aggGrid, 256, 0, stream>>>(xb, row_start, sorted_src, aggb);
    mfma_linear<1><<<linGrid, 256, 0, stream>>>(aggb, xb, Wp1, b1, xb, nullptr);

    // ---- layer 2 ----
    aggregate_mean_bf16<<<aggGrid, 256, 0, stream>>>(xb, row_start, sorted_src, aggb);
    mfma_linear<0><<<linGrid, 256, 0, stream>>>(aggb, xb, Wp2, b2, nullptr, (float*)d_out);
}